// Round 5
// baseline (688.809 us; speedup 1.0000x reference)
//
#include <hip/hip_runtime.h>
#include <hip/hip_bf16.h>

#define CH 8
#define SEC 32768
#define FIN 64
#define FOUT 64
#define UN 512
#define BM 64

typedef __bf16 bf16;
typedef bf16 bf16x8 __attribute__((ext_vector_type(8)));
typedef bf16 bf16x4 __attribute__((ext_vector_type(4)));
typedef float f32x4 __attribute__((ext_vector_type(4)));

// async global->LDS, 16B per lane; LDS dest is wave-uniform base + lane*16
__device__ __forceinline__ void gload_lds16(const void* g, void* l) {
  __builtin_amdgcn_global_load_lds(
      (const __attribute__((address_space(1))) void*)g,
      (__attribute__((address_space(3))) void*)l, 16, 0, 0);
}

template<int N>
__device__ __forceinline__ void wait_vmcnt() {
  asm volatile("s_waitcnt vmcnt(%0)" :: "i"(N) : "memory");
  __builtin_amdgcn_sched_barrier(0);  // keep following ds_reads below the wait
}

// load 8 consecutive fp32 and convert to bf16x8 (register path)
__device__ __forceinline__ bf16x8 cvt8(const float* __restrict__ src) {
  f32x4 u0 = *(const f32x4*)src;
  f32x4 u1 = *(const f32x4*)(src + 4);
  bf16x8 v;
  v[0] = (bf16)u0[0]; v[1] = (bf16)u0[1]; v[2] = (bf16)u0[2]; v[3] = (bf16)u0[3];
  v[4] = (bf16)u1[0]; v[5] = (bf16)u1[1]; v[6] = (bf16)u1[2]; v[7] = (bf16)u1[3];
  return v;
}

__device__ __forceinline__ void store_cvt8(void* dst, const float* __restrict__ src) {
  *(bf16x8*)dst = cvt8(src);
}

// ---------------------------------------------------------------------------
// Main layer: act [64 x K] (LDS, frag order [4 mt][NKS][64 lanes][16B])
//  x W[512 x K]^T -> [64 x 512], bias+relu, in-place back into act.
// 8 waves, wave w owns cols w*64..+63 (4x4 MFMA tiles).
// Weight pipeline: wave-PRIVATE 3-slot LDS ring (4 KB/slot). Each wave stages
// only the 4 fragments it reads, via global_load_lds; consumption is gated by
// counted s_waitcnt vmcnt(N) (oldest-panel accounting) -- NO barriers and NO
// vmcnt(0) drains inside the K-loop, so 2 panels stay in flight per wave.
// ---------------------------------------------------------------------------
template<int K, bool WSPATH>
__device__ __forceinline__ void run_main_layer(
    const bf16* __restrict__ wb, const float* __restrict__ wf,
    const float* __restrict__ bias, char* __restrict__ act,
    char* __restrict__ wslot,   // this wave's 12 KB ring
    int w, int l, int l15, int l4, int rot)
{
  constexpr int NKS = K / 32;
  constexpr int MASK = NKS - 1;
  const int col0 = w * 64;
  const char* abase = act + l * 16;

  f32x4 acc[4][4];
#pragma unroll
  for (int mt = 0; mt < 4; ++mt)
#pragma unroll
    for (int nt = 0; nt < 4; ++nt)
      acc[mt][nt] = f32x4{0.f, 0.f, 0.f, 0.f};

  if constexpr (WSPATH) {
    const bf16* gbase = wb + (size_t)(col0 + l15) * K + l4 * 8;

    auto stage = [&](int j, int soff) {
      const int ks = (j + rot) & MASK;
#pragma unroll
      for (int i = 0; i < 4; ++i)
        gload_lds16(gbase + (size_t)i * 16 * K + ks * 32, wslot + soff + i * 1024);
    };

    auto compute = [&](int j, int boff) {
      const int ks = (j + rot) & MASK;
      bf16x8 a[4], b[4];
#pragma unroll
      for (int nt = 0; nt < 4; ++nt)
        b[nt] = *(const bf16x8*)(wslot + boff + nt * 1024 + l * 16);
#pragma unroll
      for (int mt = 0; mt < 4; ++mt)
        a[mt] = *(const bf16x8*)(abase + (mt * NKS + ks) * 1024);
      __builtin_amdgcn_s_setprio(1);
#pragma unroll
      for (int mt = 0; mt < 4; ++mt)
#pragma unroll
        for (int nt = 0; nt < 4; ++nt)
          acc[mt][nt] = __builtin_amdgcn_mfma_f32_16x16x32_bf16(a[mt], b[nt], acc[mt][nt], 0, 0, 0);
      __builtin_amdgcn_s_setprio(0);
    };

    // prologue: panels 0 and 1 in flight (8 outstanding loads)
    stage(0, 0);
    if constexpr (NKS > 1) stage(1, 4096);

    // steady state: issue panel j+2, wait for panel j (oldest 4 of 12)
    int soff = 8192, boff = 0;
    for (int j = 0; j + 2 < NKS; ++j) {
      stage(j + 2, soff);
      soff += 4096; if (soff == 12288) soff = 0;
      wait_vmcnt<8>();
      compute(j, boff);
      boff += 4096; if (boff == 12288) boff = 0;
    }
    // tail: panels NKS-2, NKS-1
    if constexpr (NKS > 1) {
      wait_vmcnt<4>();
      compute(NKS - 2, ((NKS - 2) % 3) * 4096);
    }
    wait_vmcnt<0>();
    compute(NKS - 1, ((NKS - 1) % 3) * 4096);
  } else {
    // fallback: direct fp32->bf16 register path, no prefetch
    const float* bpf[4];
#pragma unroll
    for (int nt = 0; nt < 4; ++nt)
      bpf[nt] = wf + (size_t)(col0 + nt * 16 + l15) * K + l4 * 8;
    for (int j = 0; j < NKS; ++j) {
      const int ks = (j + rot) & MASK;
      bf16x8 a[4], b[4];
#pragma unroll
      for (int nt = 0; nt < 4; ++nt) b[nt] = cvt8(bpf[nt] + ks * 32);
#pragma unroll
      for (int mt = 0; mt < 4; ++mt)
        a[mt] = *(const bf16x8*)(abase + (mt * NKS + ks) * 1024);
#pragma unroll
      for (int mt = 0; mt < 4; ++mt)
#pragma unroll
        for (int nt = 0; nt < 4; ++nt)
          acc[mt][nt] = __builtin_amdgcn_mfma_f32_16x16x32_bf16(a[mt], b[nt], acc[mt][nt], 0, 0, 0);
    }
  }

  __syncthreads();  // all waves done reading act for this layer

  // epilogue: bias+relu -> act, next layer's frag order (next NKS = 16)
#pragma unroll
  for (int nt = 0; nt < 4; ++nt) {
    const int col = col0 + nt * 16 + l15;       // = next layer's k index
    const float bv = bias[col];
    const int base = (col >> 5) * 1024 + ((col >> 3) & 3) * 256 + (col & 7) * 2 + l4 * 64;
#pragma unroll
    for (int mt = 0; mt < 4; ++mt)
#pragma unroll
      for (int r = 0; r < 4; ++r) {
        float v = acc[mt][nt][r] + bv;
        v = v > 0.f ? v : 0.f;
        *(bf16*)(act + mt * 16384 + base + r * 16) = (bf16)v;
      }
  }
  __syncthreads();  // act ready for next layer
}

// ---------------------------------------------------------------------------
// Final layer: [64 x 512] x [64 x 512]^T -> [64 x 64] fp32 to global, no relu.
// Wave w: m-tile = w>>1, n-frags {(w&1)*2, (w&1)*2+1}. Register double-buffer
// (safe at the 256-reg budget). No barriers needed.
// ---------------------------------------------------------------------------
template<bool WSPATH>
__device__ __forceinline__ void run_final_layer(
    const bf16* __restrict__ wb, const float* __restrict__ wf,
    const float* __restrict__ bias, const char* __restrict__ act,
    float* __restrict__ gout,
    int w, int l, int l15, int l4, int rot)
{
  constexpr int NKS = 16;
  const int mt = w >> 1;
  const int nb = (w & 1) * 2;
  const char* abase = act + mt * 16384 + l * 16;

  f32x4 acc[2];
  acc[0] = f32x4{0.f, 0.f, 0.f, 0.f};
  acc[1] = f32x4{0.f, 0.f, 0.f, 0.f};

  if constexpr (WSPATH) {
    const bf16* bp0 = wb + (size_t)((nb + 0) * 16 + l15) * UN + l4 * 8;
    const bf16* bp1 = wb + (size_t)((nb + 1) * 16 + l15) * UN + l4 * 8;
    bf16x8 B0[2], B1[2];
    B0[0] = *(const bf16x8*)(bp0 + (rot & 15) * 32);
    B0[1] = *(const bf16x8*)(bp1 + (rot & 15) * 32);
#pragma unroll
    for (int j = 0; j < NKS; j += 2) {
      {
        const int ksn = (j + 1 + rot) & 15;
        B1[0] = *(const bf16x8*)(bp0 + ksn * 32);
        B1[1] = *(const bf16x8*)(bp1 + ksn * 32);
        const int ks = (j + rot) & 15;
        const bf16x8 a = *(const bf16x8*)(abase + ks * 1024);
        acc[0] = __builtin_amdgcn_mfma_f32_16x16x32_bf16(a, B0[0], acc[0], 0, 0, 0);
        acc[1] = __builtin_amdgcn_mfma_f32_16x16x32_bf16(a, B0[1], acc[1], 0, 0, 0);
      }
      {
        if (j + 2 < NKS) {
          const int ksn = (j + 2 + rot) & 15;
          B0[0] = *(const bf16x8*)(bp0 + ksn * 32);
          B0[1] = *(const bf16x8*)(bp1 + ksn * 32);
        }
        const int ks = (j + 1 + rot) & 15;
        const bf16x8 a = *(const bf16x8*)(abase + ks * 1024);
        acc[0] = __builtin_amdgcn_mfma_f32_16x16x32_bf16(a, B1[0], acc[0], 0, 0, 0);
        acc[1] = __builtin_amdgcn_mfma_f32_16x16x32_bf16(a, B1[1], acc[1], 0, 0, 0);
      }
    }
  } else {
    const float* bpf0 = wf + (size_t)((nb + 0) * 16 + l15) * UN + l4 * 8;
    const float* bpf1 = wf + (size_t)((nb + 1) * 16 + l15) * UN + l4 * 8;
    for (int j = 0; j < NKS; ++j) {
      const int ks = (j + rot) & 15;
      const bf16x8 b0 = cvt8(bpf0 + ks * 32);
      const bf16x8 b1 = cvt8(bpf1 + ks * 32);
      const bf16x8 a = *(const bf16x8*)(abase + ks * 1024);
      acc[0] = __builtin_amdgcn_mfma_f32_16x16x32_bf16(a, b0, acc[0], 0, 0, 0);
      acc[1] = __builtin_amdgcn_mfma_f32_16x16x32_bf16(a, b1, acc[1], 0, 0, 0);
    }
  }

#pragma unroll
  for (int i = 0; i < 2; ++i) {
    const int col = (nb + i) * 16 + l15;
    const float bv = bias[col];
#pragma unroll
    for (int r = 0; r < 4; ++r)
      gout[(size_t)(mt * 16 + l4 * 4 + r) * FOUT + col] = acc[i][r] + bv;
  }
}

template<bool WSPATH>
__global__ __launch_bounds__(512, 2) void mlp_fused(
    const float* __restrict__ x,
    const float* __restrict__ w0f, const float* __restrict__ w1f,
    const float* __restrict__ w2f, const float* __restrict__ w3f,
    const float* __restrict__ b0, const float* __restrict__ b1,
    const float* __restrict__ b2, const float* __restrict__ b3,
    const bf16* __restrict__ wbase,
    float* __restrict__ out)
{
  extern __shared__ char smem[];
  char* act = smem;                       // 64 KiB activations, frag order
  // 8 wave-private 12 KiB staging rings: 96 KiB -> total 160 KiB exactly

  const int tid = threadIdx.x;
  const int w = tid >> 6, l = tid & 63;
  const int l15 = l & 15, l4 = l >> 4;
  char* wslot = smem + 65536 + w * 12288;

  // XCD-chunked swizzle (4096 % 8 == 0 -> bijective): each XCD owns one channel
  const int wg = (blockIdx.x & 7) * 512 + (blockIdx.x >> 3);
  const int ch = wg >> 9;
  const int row0 = (wg & 511) * BM;
  const int rot = wg & 15;  // k-panel rotation decorrelates same-line L2 bursts

  const bf16* w0b = wbase + (size_t)ch * UN * FIN;
  const bf16* w1b = wbase + CH * UN * FIN + (size_t)ch * UN * UN;
  const bf16* w2b = wbase + CH * UN * FIN + CH * UN * UN + (size_t)ch * UN * UN;
  const bf16* w3b = wbase + CH * UN * FIN + 2 * CH * UN * UN + (size_t)ch * FOUT * UN;
  const float* w0c = w0f + (size_t)ch * UN * FIN;
  const float* w1c = w1f + (size_t)ch * UN * UN;
  const float* w2c = w2f + (size_t)ch * UN * UN;
  const float* w3c = w3f + (size_t)ch * FOUT * UN;
  const float* b0c = b0 + ch * UN;
  const float* b1c = b1 + ch * UN;
  const float* b2c = b2 + ch * UN;
  const float* b3c = b3 + ch * FOUT;

  // stage x tile (64 x 64 fp32 -> bf16) into act, frag order with NKS=2
  {
    const float* xs = x + (size_t)(ch * SEC + row0) * FIN;
    store_cvt8(act + w * 1024 + l * 16,
               xs + ((w >> 1) * 16 + l15) * FIN + (w & 1) * 32 + l4 * 8);
  }
  __syncthreads();

  run_main_layer<64,  WSPATH>(w0b, w0c, b0c, act, wslot, w, l, l15, l4, rot);
  run_main_layer<512, WSPATH>(w1b, w1c, b1c, act, wslot, w, l, l15, l4, rot);
  run_main_layer<512, WSPATH>(w2b, w2c, b2c, act, wslot, w, l, l15, l4, rot);
  run_final_layer<WSPATH>(w3b, w3c, b3c, act,
                          out + (size_t)(ch * SEC + row0) * FOUT,
                          w, l, l15, l4, rot);
}

// one-shot fp32 -> bf16 weight conversion into d_ws (layout: w0|w1|w2|w3 flat)
__global__ void cvt_weights(const float* __restrict__ w0, const float* __restrict__ w1,
                            const float* __restrict__ w2, const float* __restrict__ w3,
                            bf16* __restrict__ o)
{
  const int n0 = CH * UN * FIN;   // 262144
  const int n1 = CH * UN * UN;    // 2097152
  const int total = 2 * n0 + 2 * n1;
  for (int i4 = blockIdx.x * blockDim.x + threadIdx.x; i4 < total / 4;
       i4 += gridDim.x * blockDim.x) {
    const int idx = i4 * 4;
    const float* src; int off;
    if (idx < n0)                { src = w0; off = idx; }
    else if (idx < n0 + n1)      { src = w1; off = idx - n0; }
    else if (idx < n0 + 2 * n1)  { src = w2; off = idx - n0 - n1; }
    else                         { src = w3; off = idx - n0 - 2 * n1; }
    const f32x4 v = *(const f32x4*)(src + off);
    bf16x4 r;
    r[0] = (bf16)v[0]; r[1] = (bf16)v[1]; r[2] = (bf16)v[2]; r[3] = (bf16)v[3];
    *(bf16x4*)(o + idx) = r;
  }
}

extern "C" void kernel_launch(void* const* d_in, const int* in_sizes, int n_in,
                              void* d_out, int out_size, void* d_ws, size_t ws_size,
                              hipStream_t stream)
{
  const float* x  = (const float*)d_in[0];
  const float* w0 = (const float*)d_in[1];
  const float* w1 = (const float*)d_in[2];
  const float* w2 = (const float*)d_in[3];
  const float* w3 = (const float*)d_in[4];
  const float* b0 = (const float*)d_in[5];
  const float* b1 = (const float*)d_in[6];
  const float* b2 = (const float*)d_in[7];
  const float* b3 = (const float*)d_in[8];
  float* out = (float*)d_out;

  const int grid = CH * (SEC / BM);            // 4096 blocks
  const size_t wbytes = (size_t)(2 * CH * UN * FIN + 2 * CH * UN * UN) * 2;  // 9437184

  if (ws_size >= wbytes) {
    bf16* wb = (bf16*)d_ws;
    hipLaunchKernelGGL(cvt_weights, dim3(2048), dim3(256), 0, stream, w0, w1, w2, w3, wb);
    hipFuncSetAttribute(reinterpret_cast<const void*>(mlp_fused<true>),
                        hipFuncAttributeMaxDynamicSharedMemorySize, 163840);
    hipLaunchKernelGGL(mlp_fused<true>, dim3(grid), dim3(512), 163840, stream,
                       x, w0, w1, w2, w3, b0, b1, b2, b3, wb, out);
  } else {
    hipFuncSetAttribute(reinterpret_cast<const void*>(mlp_fused<false>),
                        hipFuncAttributeMaxDynamicSharedMemorySize, 163840);
    hipLaunchKernelGGL(mlp_fused<false>, dim3(grid), dim3(512), 163840, stream,
                       x, w0, w1, w2, w3, b0, b1, b2, b3, (const bf16*)nullptr, out);
  }
}

// Round 6
// 338.113 us; speedup vs baseline: 2.0372x; 2.0372x over previous
//
#include <hip/hip_runtime.h>
#include <hip/hip_bf16.h>

#define CH 8
#define SEC 32768
#define FIN 64
#define FOUT 64
#define UN 512
#define BM 64

typedef __bf16 bf16;
typedef bf16 bf16x8 __attribute__((ext_vector_type(8)));
typedef bf16 bf16x4 __attribute__((ext_vector_type(4)));
typedef float f32x4 __attribute__((ext_vector_type(4)));

// async global->LDS, 16B per lane; LDS dest is wave-uniform base + lane*16,
// global src is per-lane.
__device__ __forceinline__ void gload_lds16(const void* g, void* l) {
  __builtin_amdgcn_global_load_lds(
      (const __attribute__((address_space(1))) void*)g,
      (__attribute__((address_space(3))) void*)l, 16, 0, 0);
}

template<int N>
__device__ __forceinline__ void wait_vmcnt() {
  asm volatile("s_waitcnt vmcnt(%0)" :: "i"(N) : "memory");
  __builtin_amdgcn_sched_barrier(0);  // rule #18: pin following ds_reads below
}

// load 8 consecutive fp32 and convert to bf16x8
__device__ __forceinline__ bf16x8 cvt8(const float* __restrict__ src) {
  f32x4 u0 = *(const f32x4*)src;
  f32x4 u1 = *(const f32x4*)(src + 4);
  bf16x8 v;
  v[0] = (bf16)u0[0]; v[1] = (bf16)u0[1]; v[2] = (bf16)u0[2]; v[3] = (bf16)u0[3];
  v[4] = (bf16)u1[0]; v[5] = (bf16)u1[1]; v[6] = (bf16)u1[2]; v[7] = (bf16)u1[3];
  return v;
}

__device__ __forceinline__ void store_cvt8(void* dst, const float* __restrict__ src) {
  *(bf16x8*)dst = cvt8(src);
}

// ---------------------------------------------------------------------------
// Main layer: act [64 x K] (LDS, frag order [4 mt][NKS][64 lanes][16B])
//  x W[512 x K]^T -> [64 x 512], bias+relu, in-place back into act.
// 8 waves, wave w owns cols w*64..+63 (4x4 MFMA tiles).
// Weights come from the SWIZZLED d_ws layout: [frag][ks][lane][8elem] --
// every panel is a contiguous 4 KB block, so each global_load_lds reads a
// fully-contiguous 1 KB (dense 128B lines, no over-fetch, no address-pipe
// serialization). Wave-private 3-slot LDS ring + counted vmcnt, no barriers
// inside the K-loop.
// ---------------------------------------------------------------------------
template<int K, bool WSPATH>
__device__ __forceinline__ void run_main_layer(
    const bf16* __restrict__ wb,   // swizzled layout when WSPATH
    const float* __restrict__ wf,  // raw [N][K] fp32 fallback
    const float* __restrict__ bias, char* __restrict__ act,
    char* __restrict__ wslot,      // this wave's 12 KB ring
    int w, int l, int l15, int l4, int rot)
{
  constexpr int NKS = K / 32;
  constexpr int MASK = NKS - 1;
  const int col0 = w * 64;
  const char* abase = act + l * 16;

  f32x4 acc[4][4];
#pragma unroll
  for (int mt = 0; mt < 4; ++mt)
#pragma unroll
    for (int nt = 0; nt < 4; ++nt)
      acc[mt][nt] = f32x4{0.f, 0.f, 0.f, 0.f};

  if constexpr (WSPATH) {
    // per-lane src base for this wave's 4 frags: ((f*NKS+ks)*64 + l) * 8 elems
    const bf16* gbase = wb + ((size_t)(w * 4) * NKS * 64 + l) * 8;

    auto stage = [&](int j, int soff) {
      const int ks = (j + rot) & MASK;
#pragma unroll
      for (int i = 0; i < 4; ++i)
        gload_lds16(gbase + (size_t)(i * NKS + ks) * 512, wslot + soff + i * 1024);
    };

    auto compute = [&](int j, int boff) {
      const int ks = (j + rot) & MASK;
      bf16x8 a[4], b[4];
#pragma unroll
      for (int nt = 0; nt < 4; ++nt)
        b[nt] = *(const bf16x8*)(wslot + boff + nt * 1024 + l * 16);
#pragma unroll
      for (int mt = 0; mt < 4; ++mt)
        a[mt] = *(const bf16x8*)(abase + (mt * NKS + ks) * 1024);
      __builtin_amdgcn_s_setprio(1);
#pragma unroll
      for (int mt = 0; mt < 4; ++mt)
#pragma unroll
        for (int nt = 0; nt < 4; ++nt)
          acc[mt][nt] = __builtin_amdgcn_mfma_f32_16x16x32_bf16(a[mt], b[nt], acc[mt][nt], 0, 0, 0);
      __builtin_amdgcn_s_setprio(0);
    };

    // prologue: panels 0 and 1 in flight (8 outstanding loads)
    stage(0, 0);
    if constexpr (NKS > 1) stage(1, 4096);

    // steady state: issue panel j+2, wait for panel j (oldest 4 of 12)
    int soff = 8192, boff = 0;
    for (int j = 0; j + 2 < NKS; ++j) {
      stage(j + 2, soff);
      soff += 4096; if (soff == 12288) soff = 0;
      wait_vmcnt<8>();
      compute(j, boff);
      boff += 4096; if (boff == 12288) boff = 0;
    }
    if constexpr (NKS > 1) {
      wait_vmcnt<4>();
      compute(NKS - 2, ((NKS - 2) % 3) * 4096);
    }
    wait_vmcnt<0>();
    compute(NKS - 1, ((NKS - 1) % 3) * 4096);
  } else {
    // fallback: direct fp32->bf16 register path from raw layout
    const float* bpf[4];
#pragma unroll
    for (int nt = 0; nt < 4; ++nt)
      bpf[nt] = wf + (size_t)(col0 + nt * 16 + l15) * K + l4 * 8;
    for (int j = 0; j < NKS; ++j) {
      const int ks = (j + rot) & MASK;
      bf16x8 a[4], b[4];
#pragma unroll
      for (int nt = 0; nt < 4; ++nt) b[nt] = cvt8(bpf[nt] + ks * 32);
#pragma unroll
      for (int mt = 0; mt < 4; ++mt)
        a[mt] = *(const bf16x8*)(abase + (mt * NKS + ks) * 1024);
#pragma unroll
      for (int mt = 0; mt < 4; ++mt)
#pragma unroll
        for (int nt = 0; nt < 4; ++nt)
          acc[mt][nt] = __builtin_amdgcn_mfma_f32_16x16x32_bf16(a[mt], b[nt], acc[mt][nt], 0, 0, 0);
    }
  }

  __syncthreads();  // all waves done reading act for this layer

  // epilogue: bias+relu -> act, next layer's frag order (next NKS = 16)
#pragma unroll
  for (int nt = 0; nt < 4; ++nt) {
    const int col = col0 + nt * 16 + l15;       // = next layer's k index
    const float bv = bias[col];
    const int base = (col >> 5) * 1024 + ((col >> 3) & 3) * 256 + (col & 7) * 2 + l4 * 64;
#pragma unroll
    for (int mt = 0; mt < 4; ++mt)
#pragma unroll
      for (int r = 0; r < 4; ++r) {
        float v = acc[mt][nt][r] + bv;
        v = v > 0.f ? v : 0.f;
        *(bf16*)(act + mt * 16384 + base + r * 16) = (bf16)v;
      }
  }
  __syncthreads();  // act ready for next layer
}

// ---------------------------------------------------------------------------
// Final layer: [64 x 512] x [64 x 512]^T -> [64 x 64] fp32 to global, no relu.
// Wave w: m-tile = w>>1, n-frags {(w&1)*2, (w&1)*2+1}. Register double-buffer
// from the swizzled layout (contiguous 16B/lane). No barriers.
// ---------------------------------------------------------------------------
template<bool WSPATH>
__device__ __forceinline__ void run_final_layer(
    const bf16* __restrict__ wb, const float* __restrict__ wf,
    const float* __restrict__ bias, const char* __restrict__ act,
    float* __restrict__ gout,
    int w, int l, int l15, int l4, int rot)
{
  constexpr int NKS = 16;
  const int mt = w >> 1;
  const int nb = (w & 1) * 2;
  const char* abase = act + mt * 16384 + l * 16;

  f32x4 acc[2];
  acc[0] = f32x4{0.f, 0.f, 0.f, 0.f};
  acc[1] = f32x4{0.f, 0.f, 0.f, 0.f};

  if constexpr (WSPATH) {
    // swizzled: frag f at ((f*16 + ks)*64 + l)*8
    const bf16* bp0 = wb + ((size_t)(nb + 0) * 16 * 64 + l) * 8;
    const bf16* bp1 = wb + ((size_t)(nb + 1) * 16 * 64 + l) * 8;
    bf16x8 B0[2], B1[2];
    B0[0] = *(const bf16x8*)(bp0 + (size_t)(rot & 15) * 512);
    B0[1] = *(const bf16x8*)(bp1 + (size_t)(rot & 15) * 512);
#pragma unroll
    for (int j = 0; j < NKS; j += 2) {
      {
        const int ksn = (j + 1 + rot) & 15;
        B1[0] = *(const bf16x8*)(bp0 + (size_t)ksn * 512);
        B1[1] = *(const bf16x8*)(bp1 + (size_t)ksn * 512);
        const int ks = (j + rot) & 15;
        const bf16x8 a = *(const bf16x8*)(abase + ks * 1024);
        acc[0] = __builtin_amdgcn_mfma_f32_16x16x32_bf16(a, B0[0], acc[0], 0, 0, 0);
        acc[1] = __builtin_amdgcn_mfma_f32_16x16x32_bf16(a, B0[1], acc[1], 0, 0, 0);
      }
      {
        if (j + 2 < NKS) {
          const int ksn = (j + 2 + rot) & 15;
          B0[0] = *(const bf16x8*)(bp0 + (size_t)ksn * 512);
          B0[1] = *(const bf16x8*)(bp1 + (size_t)ksn * 512);
        }
        const int ks = (j + 1 + rot) & 15;
        const bf16x8 a = *(const bf16x8*)(abase + ks * 1024);
        acc[0] = __builtin_amdgcn_mfma_f32_16x16x32_bf16(a, B1[0], acc[0], 0, 0, 0);
        acc[1] = __builtin_amdgcn_mfma_f32_16x16x32_bf16(a, B1[1], acc[1], 0, 0, 0);
      }
    }
  } else {
    const float* bpf0 = wf + (size_t)((nb + 0) * 16 + l15) * UN + l4 * 8;
    const float* bpf1 = wf + (size_t)((nb + 1) * 16 + l15) * UN + l4 * 8;
    for (int j = 0; j < NKS; ++j) {
      const int ks = (j + rot) & 15;
      const bf16x8 b0 = cvt8(bpf0 + ks * 32);
      const bf16x8 b1 = cvt8(bpf1 + ks * 32);
      const bf16x8 a = *(const bf16x8*)(abase + ks * 1024);
      acc[0] = __builtin_amdgcn_mfma_f32_16x16x32_bf16(a, b0, acc[0], 0, 0, 0);
      acc[1] = __builtin_amdgcn_mfma_f32_16x16x32_bf16(a, b1, acc[1], 0, 0, 0);
    }
  }

#pragma unroll
  for (int i = 0; i < 2; ++i) {
    const int col = (nb + i) * 16 + l15;
    const float bv = bias[col];
#pragma unroll
    for (int r = 0; r < 4; ++r)
      gout[(size_t)(mt * 16 + l4 * 4 + r) * FOUT + col] = acc[i][r] + bv;
  }
}

template<bool WSPATH>
__global__ __launch_bounds__(512, 2) void mlp_fused(
    const float* __restrict__ x,
    const float* __restrict__ w0f, const float* __restrict__ w1f,
    const float* __restrict__ w2f, const float* __restrict__ w3f,
    const float* __restrict__ b0, const float* __restrict__ b1,
    const float* __restrict__ b2, const float* __restrict__ b3,
    const bf16* __restrict__ wbase,
    float* __restrict__ out)
{
  extern __shared__ char smem[];
  char* act = smem;                       // 64 KiB activations, frag order
  // + 8 wave-private 12 KiB staging rings = 160 KiB exactly

  const int tid = threadIdx.x;
  const int w = tid >> 6, l = tid & 63;
  const int l15 = l & 15, l4 = l >> 4;
  char* wslot = smem + 65536 + w * 12288;

  // XCD-chunked swizzle (4096 % 8 == 0 -> bijective): each XCD owns one channel
  const int wg = (blockIdx.x & 7) * 512 + (blockIdx.x >> 3);
  const int ch = wg >> 9;
  const int row0 = (wg & 511) * BM;
  const int rot = wg & 15;  // k-panel rotation decorrelates same-line L2 bursts

  const bf16* w0b = wbase + (size_t)ch * UN * FIN;
  const bf16* w1b = wbase + CH * UN * FIN + (size_t)ch * UN * UN;
  const bf16* w2b = wbase + CH * UN * FIN + CH * UN * UN + (size_t)ch * UN * UN;
  const bf16* w3b = wbase + CH * UN * FIN + 2 * CH * UN * UN + (size_t)ch * FOUT * UN;
  const float* w0c = w0f + (size_t)ch * UN * FIN;
  const float* w1c = w1f + (size_t)ch * UN * UN;
  const float* w2c = w2f + (size_t)ch * UN * UN;
  const float* w3c = w3f + (size_t)ch * FOUT * UN;
  const float* b0c = b0 + ch * UN;
  const float* b1c = b1 + ch * UN;
  const float* b2c = b2 + ch * UN;
  const float* b3c = b3 + ch * FOUT;

  // stage x tile (64 x 64 fp32 -> bf16) into act, frag order with NKS=2
  {
    const float* xs = x + (size_t)(ch * SEC + row0) * FIN;
    store_cvt8(act + w * 1024 + l * 16,
               xs + ((w >> 1) * 16 + l15) * FIN + (w & 1) * 32 + l4 * 8);
  }
  __syncthreads();

  run_main_layer<64,  WSPATH>(w0b, w0c, b0c, act, wslot, w, l, l15, l4, rot);
  run_main_layer<512, WSPATH>(w1b, w1c, b1c, act, wslot, w, l, l15, l4, rot);
  run_main_layer<512, WSPATH>(w2b, w2c, b2c, act, wslot, w, l, l15, l4, rot);
  run_final_layer<WSPATH>(w3b, w3c, b3c, act,
                          out + (size_t)(ch * SEC + row0) * FOUT,
                          w, l, l15, l4, rot);
}

// ---------------------------------------------------------------------------
// fp32 -> bf16 weight conversion into d_ws, SWIZZLED to MFMA-fragment order:
// per channel, element (f, ks, l, j) = W[f*16 + (l&15)][ks*32 + (l>>4)*8 + j]
// stored at ((f*NKS + ks)*64 + l)*8 + j. One thread per (ch,f,ks,l) triple.
// ---------------------------------------------------------------------------
template<int K, int N>
__device__ __forceinline__ void cvt_one(const float* __restrict__ src,
                                        bf16* __restrict__ dst, int t)
{
  constexpr int NKS = K / 32;
  constexpr int perCh = N * K / 8;   // triples per channel (pow2)
  const int ch = t / perCh;
  const int r = t - ch * perCh;
  const int l = r & 63;
  const int p = r >> 6;
  const int ks = p & (NKS - 1);
  const int f = p / NKS;
  const float* s = src + (size_t)ch * N * K + (size_t)(f * 16 + (l & 15)) * K
                 + ks * 32 + (l >> 4) * 8;
  store_cvt8(dst + (size_t)t * 8, s);
}

__global__ void cvt_weights(const float* __restrict__ w0, const float* __restrict__ w1,
                            const float* __restrict__ w2, const float* __restrict__ w3,
                            bf16* __restrict__ o)
{
  constexpr int T0 = CH * UN * FIN / 8;   // 32768 triples
  constexpr int T1 = CH * UN * UN / 8;    // 262144
  constexpr int total = 2 * T0 + 2 * T1;  // 589824
  for (int t = blockIdx.x * blockDim.x + threadIdx.x; t < total;
       t += gridDim.x * blockDim.x) {
    if (t < T0)                cvt_one<FIN, UN>(w0, o, t);
    else if (t < T0 + T1)      cvt_one<UN, UN>(w1, o + CH * UN * FIN, t - T0);
    else if (t < T0 + 2 * T1)  cvt_one<UN, UN>(w2, o + CH * UN * FIN + CH * UN * UN, t - T0 - T1);
    else                       cvt_one<UN, FOUT>(w3, o + CH * UN * FIN + 2 * CH * UN * UN, t - T0 - 2 * T1);
  }
}

extern "C" void kernel_launch(void* const* d_in, const int* in_sizes, int n_in,
                              void* d_out, int out_size, void* d_ws, size_t ws_size,
                              hipStream_t stream)
{
  const float* x  = (const float*)d_in[0];
  const float* w0 = (const float*)d_in[1];
  const float* w1 = (const float*)d_in[2];
  const float* w2 = (const float*)d_in[3];
  const float* w3 = (const float*)d_in[4];
  const float* b0 = (const float*)d_in[5];
  const float* b1 = (const float*)d_in[6];
  const float* b2 = (const float*)d_in[7];
  const float* b3 = (const float*)d_in[8];
  float* out = (float*)d_out;

  const int grid = CH * (SEC / BM);            // 4096 blocks
  const size_t wbytes = (size_t)(2 * CH * UN * FIN + 2 * CH * UN * UN) * 2;  // 9437184

  if (ws_size >= wbytes) {
    bf16* wb = (bf16*)d_ws;
    hipLaunchKernelGGL(cvt_weights, dim3(2304), dim3(256), 0, stream, w0, w1, w2, w3, wb);
    hipFuncSetAttribute(reinterpret_cast<const void*>(mlp_fused<true>),
                        hipFuncAttributeMaxDynamicSharedMemorySize, 163840);
    hipLaunchKernelGGL(mlp_fused<true>, dim3(grid), dim3(512), 163840, stream,
                       x, w0, w1, w2, w3, b0, b1, b2, b3, wb, out);
  } else {
    hipFuncSetAttribute(reinterpret_cast<const void*>(mlp_fused<false>),
                        hipFuncAttributeMaxDynamicSharedMemorySize, 163840);
    hipLaunchKernelGGL(mlp_fused<false>, dim3(grid), dim3(512), 163840, stream,
                       x, w0, w1, w2, w3, b0, b1, b2, b3, (const bf16*)nullptr, out);
  }
}

// Round 7
// 309.456 us; speedup vs baseline: 2.2259x; 1.0926x over previous
//
#include <hip/hip_runtime.h>
#include <hip/hip_bf16.h>

#define CH 8
#define SEC 32768
#define FIN 64
#define FOUT 64
#define UN 512
#define BM 64

typedef __bf16 bf16;
typedef bf16 bf16x8 __attribute__((ext_vector_type(8)));
typedef bf16 bf16x4 __attribute__((ext_vector_type(4)));
typedef float f32x4 __attribute__((ext_vector_type(4)));

// load 8 consecutive fp32 and convert to bf16x8
__device__ __forceinline__ bf16x8 cvt8(const float* __restrict__ src) {
  f32x4 u0 = *(const f32x4*)src;
  f32x4 u1 = *(const f32x4*)(src + 4);
  bf16x8 v;
  v[0] = (bf16)u0[0]; v[1] = (bf16)u0[1]; v[2] = (bf16)u0[2]; v[3] = (bf16)u0[3];
  v[4] = (bf16)u1[0]; v[5] = (bf16)u1[1]; v[6] = (bf16)u1[2]; v[7] = (bf16)u1[3];
  return v;
}

__device__ __forceinline__ void store_cvt8(void* dst, const float* __restrict__ src) {
  *(bf16x8*)dst = cvt8(src);
}

// ---------------------------------------------------------------------------
// Main layer: act [64 x K] (LDS, frag order [4 mt][NKS][64 lanes][16B])
//  x W[512 x K]^T -> [64 x 512], bias+relu, in-place back into act.
// 8 waves, wave w owns cols w*64..+63 (4x4 MFMA tiles).
// B-panels are wave-private -> load GLOBAL->REGISTERS directly from the
// swizzled d_ws layout (16B/lane contiguous, coalesced), double-buffered
// B0/B1 with static alternation (unroll j+=2). No LDS for weights at all:
// LDS read traffic halves (A only), no barriers or waitcnt in the K-loop.
// Budget: __launch_bounds__(512,2) -> 256 VGPRs, no spill (acc64+dbuf32+a16).
// ---------------------------------------------------------------------------
template<int K, bool WSPATH>
__device__ __forceinline__ void run_main_layer(
    const bf16* __restrict__ wb,   // swizzled layout when WSPATH
    const float* __restrict__ wf,  // raw [N][K] fp32 fallback
    const float* __restrict__ bias, char* __restrict__ act,
    int w, int l, int l15, int l4, int rot)
{
  constexpr int NKS = K / 32;
  constexpr int MASK = NKS - 1;
  const int col0 = w * 64;
  const char* abase = act + l * 16;

  f32x4 acc[4][4];
#pragma unroll
  for (int mt = 0; mt < 4; ++mt)
#pragma unroll
    for (int nt = 0; nt < 4; ++nt)
      acc[mt][nt] = f32x4{0.f, 0.f, 0.f, 0.f};

  if constexpr (WSPATH) {
    // per-lane base: wave w's frag i, panel ks at bp + (i*NKS + ks)*512 elems
    const bf16* bp = wb + ((size_t)(w * 4) * NKS * 64 + l) * 8;

    bf16x8 B0[4], B1[4];
    {
      const int ks0 = rot & MASK;
#pragma unroll
      for (int i = 0; i < 4; ++i)
        B0[i] = *(const bf16x8*)(bp + ((size_t)i * NKS + ks0) * 512);
    }

#pragma unroll
    for (int j = 0; j < NKS; j += 2) {
      {  // compute panel j with B0, prefetch j+1 into B1
        const int ksn = (j + 1 + rot) & MASK;
#pragma unroll
        for (int i = 0; i < 4; ++i)
          B1[i] = *(const bf16x8*)(bp + ((size_t)i * NKS + ksn) * 512);
        const int ks = (j + rot) & MASK;
        bf16x8 a[4];
#pragma unroll
        for (int mt = 0; mt < 4; ++mt)
          a[mt] = *(const bf16x8*)(abase + (mt * NKS + ks) * 1024);
        __builtin_amdgcn_s_setprio(1);
#pragma unroll
        for (int mt = 0; mt < 4; ++mt)
#pragma unroll
          for (int nt = 0; nt < 4; ++nt)
            acc[mt][nt] = __builtin_amdgcn_mfma_f32_16x16x32_bf16(a[mt], B0[nt], acc[mt][nt], 0, 0, 0);
        __builtin_amdgcn_s_setprio(0);
      }
      {  // compute panel j+1 with B1, prefetch j+2 into B0
        if (j + 2 < NKS) {
          const int ksn = (j + 2 + rot) & MASK;
#pragma unroll
          for (int i = 0; i < 4; ++i)
            B0[i] = *(const bf16x8*)(bp + ((size_t)i * NKS + ksn) * 512);
        }
        const int ks = (j + 1 + rot) & MASK;
        bf16x8 a[4];
#pragma unroll
        for (int mt = 0; mt < 4; ++mt)
          a[mt] = *(const bf16x8*)(abase + (mt * NKS + ks) * 1024);
        __builtin_amdgcn_s_setprio(1);
#pragma unroll
        for (int mt = 0; mt < 4; ++mt)
#pragma unroll
          for (int nt = 0; nt < 4; ++nt)
            acc[mt][nt] = __builtin_amdgcn_mfma_f32_16x16x32_bf16(a[mt], B1[nt], acc[mt][nt], 0, 0, 0);
        __builtin_amdgcn_s_setprio(0);
      }
    }
  } else {
    // fallback: direct fp32->bf16 register path from raw layout
    const float* bpf[4];
#pragma unroll
    for (int nt = 0; nt < 4; ++nt)
      bpf[nt] = wf + (size_t)(col0 + nt * 16 + l15) * K + l4 * 8;
    for (int j = 0; j < NKS; ++j) {
      const int ks = (j + rot) & MASK;
      bf16x8 a[4], b[4];
#pragma unroll
      for (int nt = 0; nt < 4; ++nt) b[nt] = cvt8(bpf[nt] + ks * 32);
#pragma unroll
      for (int mt = 0; mt < 4; ++mt)
        a[mt] = *(const bf16x8*)(abase + (mt * NKS + ks) * 1024);
#pragma unroll
      for (int mt = 0; mt < 4; ++mt)
#pragma unroll
        for (int nt = 0; nt < 4; ++nt)
          acc[mt][nt] = __builtin_amdgcn_mfma_f32_16x16x32_bf16(a[mt], b[nt], acc[mt][nt], 0, 0, 0);
    }
  }

  __syncthreads();  // all waves done reading act for this layer

  // epilogue: bias+relu -> act, next layer's frag order (next NKS = 16)
#pragma unroll
  for (int nt = 0; nt < 4; ++nt) {
    const int col = col0 + nt * 16 + l15;       // = next layer's k index
    const float bv = bias[col];
    const int base = (col >> 5) * 1024 + ((col >> 3) & 3) * 256 + (col & 7) * 2 + l4 * 64;
#pragma unroll
    for (int mt = 0; mt < 4; ++mt)
#pragma unroll
      for (int r = 0; r < 4; ++r) {
        float v = acc[mt][nt][r] + bv;
        v = v > 0.f ? v : 0.f;
        *(bf16*)(act + mt * 16384 + base + r * 16) = (bf16)v;
      }
  }
  __syncthreads();  // act ready for next layer
}

// ---------------------------------------------------------------------------
// Final layer: [64 x 512] x [64 x 512]^T -> [64 x 64] fp32 to global, no relu.
// Wave w: m-tile = w>>1, n-frags {(w&1)*2, (w&1)*2+1}. Register double-buffer
// from the swizzled layout (contiguous 16B/lane). No barriers.
// ---------------------------------------------------------------------------
template<bool WSPATH>
__device__ __forceinline__ void run_final_layer(
    const bf16* __restrict__ wb, const float* __restrict__ wf,
    const float* __restrict__ bias, const char* __restrict__ act,
    float* __restrict__ gout,
    int w, int l, int l15, int l4, int rot)
{
  constexpr int NKS = 16;
  const int mt = w >> 1;
  const int nb = (w & 1) * 2;
  const char* abase = act + mt * 16384 + l * 16;

  f32x4 acc[2];
  acc[0] = f32x4{0.f, 0.f, 0.f, 0.f};
  acc[1] = f32x4{0.f, 0.f, 0.f, 0.f};

  if constexpr (WSPATH) {
    // swizzled: frag f at ((f*16 + ks)*64 + l)*8
    const bf16* bp0 = wb + ((size_t)(nb + 0) * 16 * 64 + l) * 8;
    const bf16* bp1 = wb + ((size_t)(nb + 1) * 16 * 64 + l) * 8;
    bf16x8 B0[2], B1[2];
    B0[0] = *(const bf16x8*)(bp0 + (size_t)(rot & 15) * 512);
    B0[1] = *(const bf16x8*)(bp1 + (size_t)(rot & 15) * 512);
#pragma unroll
    for (int j = 0; j < NKS; j += 2) {
      {
        const int ksn = (j + 1 + rot) & 15;
        B1[0] = *(const bf16x8*)(bp0 + (size_t)ksn * 512);
        B1[1] = *(const bf16x8*)(bp1 + (size_t)ksn * 512);
        const int ks = (j + rot) & 15;
        const bf16x8 a = *(const bf16x8*)(abase + ks * 1024);
        acc[0] = __builtin_amdgcn_mfma_f32_16x16x32_bf16(a, B0[0], acc[0], 0, 0, 0);
        acc[1] = __builtin_amdgcn_mfma_f32_16x16x32_bf16(a, B0[1], acc[1], 0, 0, 0);
      }
      {
        if (j + 2 < NKS) {
          const int ksn = (j + 2 + rot) & 15;
          B0[0] = *(const bf16x8*)(bp0 + (size_t)ksn * 512);
          B0[1] = *(const bf16x8*)(bp1 + (size_t)ksn * 512);
        }
        const int ks = (j + 1 + rot) & 15;
        const bf16x8 a = *(const bf16x8*)(abase + ks * 1024);
        acc[0] = __builtin_amdgcn_mfma_f32_16x16x32_bf16(a, B1[0], acc[0], 0, 0, 0);
        acc[1] = __builtin_amdgcn_mfma_f32_16x16x32_bf16(a, B1[1], acc[1], 0, 0, 0);
      }
    }
  } else {
    const float* bpf0 = wf + (size_t)((nb + 0) * 16 + l15) * UN + l4 * 8;
    const float* bpf1 = wf + (size_t)((nb + 1) * 16 + l15) * UN + l4 * 8;
    for (int j = 0; j < NKS; ++j) {
      const int ks = (j + rot) & 15;
      const bf16x8 b0 = cvt8(bpf0 + ks * 32);
      const bf16x8 b1 = cvt8(bpf1 + ks * 32);
      const bf16x8 a = *(const bf16x8*)(abase + ks * 1024);
      acc[0] = __builtin_amdgcn_mfma_f32_16x16x32_bf16(a, b0, acc[0], 0, 0, 0);
      acc[1] = __builtin_amdgcn_mfma_f32_16x16x32_bf16(a, b1, acc[1], 0, 0, 0);
    }
  }

#pragma unroll
  for (int i = 0; i < 2; ++i) {
    const int col = (nb + i) * 16 + l15;
    const float bv = bias[col];
#pragma unroll
    for (int r = 0; r < 4; ++r)
      gout[(size_t)(mt * 16 + l4 * 4 + r) * FOUT + col] = acc[i][r] + bv;
  }
}

template<bool WSPATH>
__global__ __launch_bounds__(512, 2) void mlp_fused(
    const float* __restrict__ x,
    const float* __restrict__ w0f, const float* __restrict__ w1f,
    const float* __restrict__ w2f, const float* __restrict__ w3f,
    const float* __restrict__ b0, const float* __restrict__ b1,
    const float* __restrict__ b2, const float* __restrict__ b3,
    const bf16* __restrict__ wbase,
    float* __restrict__ out)
{
  extern __shared__ char smem[];
  char* act = smem;  // 64 KiB activations, frag order (only LDS use)

  const int tid = threadIdx.x;
  const int w = tid >> 6, l = tid & 63;
  const int l15 = l & 15, l4 = l >> 4;

  // XCD-chunked swizzle (4096 % 8 == 0 -> bijective): each XCD owns one channel
  const int wg = (blockIdx.x & 7) * 512 + (blockIdx.x >> 3);
  const int ch = wg >> 9;
  const int row0 = (wg & 511) * BM;
  const int rot = wg & 15;  // k-panel rotation decorrelates same-line L2 bursts

  const bf16* w0b = wbase + (size_t)ch * UN * FIN;
  const bf16* w1b = wbase + CH * UN * FIN + (size_t)ch * UN * UN;
  const bf16* w2b = wbase + CH * UN * FIN + CH * UN * UN + (size_t)ch * UN * UN;
  const bf16* w3b = wbase + CH * UN * FIN + 2 * CH * UN * UN + (size_t)ch * FOUT * UN;
  const float* w0c = w0f + (size_t)ch * UN * FIN;
  const float* w1c = w1f + (size_t)ch * UN * UN;
  const float* w2c = w2f + (size_t)ch * UN * UN;
  const float* w3c = w3f + (size_t)ch * FOUT * UN;
  const float* b0c = b0 + ch * UN;
  const float* b1c = b1 + ch * UN;
  const float* b2c = b2 + ch * UN;
  const float* b3c = b3 + ch * FOUT;

  // stage x tile (64 x 64 fp32 -> bf16) into act, frag order with NKS=2
  {
    const float* xs = x + (size_t)(ch * SEC + row0) * FIN;
    store_cvt8(act + w * 1024 + l * 16,
               xs + ((w >> 1) * 16 + l15) * FIN + (w & 1) * 32 + l4 * 8);
  }
  __syncthreads();

  run_main_layer<64,  WSPATH>(w0b, w0c, b0c, act, w, l, l15, l4, rot);
  run_main_layer<512, WSPATH>(w1b, w1c, b1c, act, w, l, l15, l4, rot);
  run_main_layer<512, WSPATH>(w2b, w2c, b2c, act, w, l, l15, l4, rot);
  run_final_layer<WSPATH>(w3b, w3c, b3c, act,
                          out + (size_t)(ch * SEC + row0) * FOUT,
                          w, l, l15, l4, rot);
}

// ---------------------------------------------------------------------------
// fp32 -> bf16 weight conversion into d_ws, SWIZZLED to MFMA-fragment order:
// per channel, element (f, ks, l, j) = W[f*16 + (l&15)][ks*32 + (l>>4)*8 + j]
// stored at ((f*NKS + ks)*64 + l)*8 + j. One thread per (ch,f,ks,l) triple.
// ---------------------------------------------------------------------------
template<int K, int N>
__device__ __forceinline__ void cvt_one(const float* __restrict__ src,
                                        bf16* __restrict__ dst, int t)
{
  constexpr int NKS = K / 32;
  constexpr int perCh = N * K / 8;   // triples per channel (pow2)
  const int ch = t / perCh;
  const int r = t - ch * perCh;
  const int l = r & 63;
  const int p = r >> 6;
  const int ks = p & (NKS - 1);
  const int f = p / NKS;
  const float* s = src + (size_t)ch * N * K + (size_t)(f * 16 + (l & 15)) * K
                 + ks * 32 + (l >> 4) * 8;
  store_cvt8(dst + (size_t)t * 8, s);
}

__global__ void cvt_weights(const float* __restrict__ w0, const float* __restrict__ w1,
                            const float* __restrict__ w2, const float* __restrict__ w3,
                            bf16* __restrict__ o)
{
  constexpr int T0 = CH * UN * FIN / 8;   // 32768 triples
  constexpr int T1 = CH * UN * UN / 8;    // 262144
  constexpr int total = 2 * T0 + 2 * T1;  // 589824
  for (int t = blockIdx.x * blockDim.x + threadIdx.x; t < total;
       t += gridDim.x * blockDim.x) {
    if (t < T0)                cvt_one<FIN, UN>(w0, o, t);
    else if (t < T0 + T1)      cvt_one<UN, UN>(w1, o + CH * UN * FIN, t - T0);
    else if (t < T0 + 2 * T1)  cvt_one<UN, UN>(w2, o + CH * UN * FIN + CH * UN * UN, t - T0 - T1);
    else                       cvt_one<UN, FOUT>(w3, o + CH * UN * FIN + 2 * CH * UN * UN, t - T0 - 2 * T1);
  }
}

extern "C" void kernel_launch(void* const* d_in, const int* in_sizes, int n_in,
                              void* d_out, int out_size, void* d_ws, size_t ws_size,
                              hipStream_t stream)
{
  const float* x  = (const float*)d_in[0];
  const float* w0 = (const float*)d_in[1];
  const float* w1 = (const float*)d_in[2];
  const float* w2 = (const float*)d_in[3];
  const float* w3 = (const float*)d_in[4];
  const float* b0 = (const float*)d_in[5];
  const float* b1 = (const float*)d_in[6];
  const float* b2 = (const float*)d_in[7];
  const float* b3 = (const float*)d_in[8];
  float* out = (float*)d_out;

  const int grid = CH * (SEC / BM);            // 4096 blocks
  const size_t wbytes = (size_t)(2 * CH * UN * FIN + 2 * CH * UN * UN) * 2;  // 9437184

  if (ws_size >= wbytes) {
    bf16* wb = (bf16*)d_ws;
    hipLaunchKernelGGL(cvt_weights, dim3(2304), dim3(256), 0, stream, w0, w1, w2, w3, wb);
    hipFuncSetAttribute(reinterpret_cast<const void*>(mlp_fused<true>),
                        hipFuncAttributeMaxDynamicSharedMemorySize, 65536);
    hipLaunchKernelGGL(mlp_fused<true>, dim3(grid), dim3(512), 65536, stream,
                       x, w0, w1, w2, w3, b0, b1, b2, b3, wb, out);
  } else {
    hipFuncSetAttribute(reinterpret_cast<const void*>(mlp_fused<false>),
                        hipFuncAttributeMaxDynamicSharedMemorySize, 65536);
    hipLaunchKernelGGL(mlp_fused<false>, dim3(grid), dim3(512), 65536, stream,
                       x, w0, w1, w2, w3, b0, b1, b2, b3, (const bf16*)nullptr, out);
  }
}

// Round 8
// 302.848 us; speedup vs baseline: 2.2744x; 1.0218x over previous
//
#include <hip/hip_runtime.h>
#include <hip/hip_bf16.h>

#define CH 8
#define SEC 32768
#define FIN 64
#define FOUT 64
#define UN 512
#define BM 64

typedef __bf16 bf16;
typedef bf16 bf16x8 __attribute__((ext_vector_type(8)));
typedef bf16 bf16x4 __attribute__((ext_vector_type(4)));
typedef float f32x4 __attribute__((ext_vector_type(4)));

// load 8 consecutive fp32 and convert to bf16x8
__device__ __forceinline__ bf16x8 cvt8(const float* __restrict__ src) {
  f32x4 u0 = *(const f32x4*)src;
  f32x4 u1 = *(const f32x4*)(src + 4);
  bf16x8 v;
  v[0] = (bf16)u0[0]; v[1] = (bf16)u0[1]; v[2] = (bf16)u0[2]; v[3] = (bf16)u0[3];
  v[4] = (bf16)u1[0]; v[5] = (bf16)u1[1]; v[6] = (bf16)u1[2]; v[7] = (bf16)u1[3];
  return v;
}

__device__ __forceinline__ void store_cvt8(void* dst, const float* __restrict__ src) {
  *(bf16x8*)dst = cvt8(src);
}

// ---------------------------------------------------------------------------
// Main layer, SWAPPED MFMA OPERANDS: acc = mfma(A=W_frag, B=X_frag).
// D = W(16n x 32k) x X^T(32k x 16m) -> D[n][m]; lane: m = l15 (batch row),
// n-quad = l4*4+r (output features). So each thread holds 4 CONSECUTIVE
// output features of one row -> epilogue packs them (2x cvt_pk) into ONE
// 8-byte ds_write_b64 in the next layer's frag order:
//   element (m, n):  n>>5 = ks' = w*2 + (nt>>1)
//                    reader-lane = l15 + 16*((nt&1)*2 + (l4>>1))
//                    byte-in-slot = (l4&1)*8 + r*2
// (verified: reader act[(mt*16+ks)*1024 + l'*16 + j*2] = (m=mt*16+(l'&15),
//  k=ks*32+(l'>>4)*8+j) matches exactly.)
// X-operand (B) frag layout is identical to A's, so K-loop ds_read_b128
// and the act layout are unchanged. No `rot`: all offsets are compile-time.
// ---------------------------------------------------------------------------
template<int K, bool WSPATH>
__device__ __forceinline__ void run_main_layer(
    const bf16* __restrict__ wb,   // swizzled layout when WSPATH
    const float* __restrict__ wf,  // raw [N][K] fp32 fallback
    const float* __restrict__ bias, char* __restrict__ act,
    int w, int l, int l15, int l4)
{
  constexpr int NKS = K / 32;
  const int col0 = w * 64;
  const char* abase = act + l * 16;

  f32x4 acc[4][4];   // [mt][nt]
#pragma unroll
  for (int mt = 0; mt < 4; ++mt)
#pragma unroll
    for (int nt = 0; nt < 4; ++nt)
      acc[mt][nt] = f32x4{0.f, 0.f, 0.f, 0.f};

  if constexpr (WSPATH) {
    const bf16* bp = wb + ((size_t)(w * 4) * NKS * 64 + l) * 8;
    bf16x8 B0[4], B1[4];
#pragma unroll
    for (int i = 0; i < 4; ++i)
      B0[i] = *(const bf16x8*)(bp + (size_t)(i * NKS) * 512);

#pragma unroll
    for (int j = 0; j < NKS; j += 2) {
      if (j + 1 < NKS) {
#pragma unroll
        for (int i = 0; i < 4; ++i)
          B1[i] = *(const bf16x8*)(bp + (size_t)(i * NKS + j + 1) * 512);
      }
      {
        bf16x8 a[4];
#pragma unroll
        for (int mt = 0; mt < 4; ++mt)
          a[mt] = *(const bf16x8*)(abase + (mt * NKS + j) * 1024);
        __builtin_amdgcn_s_setprio(1);
#pragma unroll
        for (int mt = 0; mt < 4; ++mt)
#pragma unroll
          for (int nt = 0; nt < 4; ++nt)
            acc[mt][nt] = __builtin_amdgcn_mfma_f32_16x16x32_bf16(B0[nt], a[mt], acc[mt][nt], 0, 0, 0);
        __builtin_amdgcn_s_setprio(0);
      }
      if (j + 2 < NKS) {
#pragma unroll
        for (int i = 0; i < 4; ++i)
          B0[i] = *(const bf16x8*)(bp + (size_t)(i * NKS + j + 2) * 512);
      }
      if (j + 1 < NKS) {
        bf16x8 a[4];
#pragma unroll
        for (int mt = 0; mt < 4; ++mt)
          a[mt] = *(const bf16x8*)(abase + (mt * NKS + j + 1) * 1024);
        __builtin_amdgcn_s_setprio(1);
#pragma unroll
        for (int mt = 0; mt < 4; ++mt)
#pragma unroll
          for (int nt = 0; nt < 4; ++nt)
            acc[mt][nt] = __builtin_amdgcn_mfma_f32_16x16x32_bf16(B1[nt], a[mt], acc[mt][nt], 0, 0, 0);
        __builtin_amdgcn_s_setprio(0);
      }
    }
  } else {
    // fallback: direct fp32->bf16 register path from raw layout
    const float* bpf[4];
#pragma unroll
    for (int nt = 0; nt < 4; ++nt)
      bpf[nt] = wf + (size_t)(col0 + nt * 16 + l15) * K + l4 * 8;
#pragma unroll
    for (int j = 0; j < NKS; ++j) {
      bf16x8 a[4], b[4];
#pragma unroll
      for (int nt = 0; nt < 4; ++nt) b[nt] = cvt8(bpf[nt] + j * 32);
#pragma unroll
      for (int mt = 0; mt < 4; ++mt)
        a[mt] = *(const bf16x8*)(abase + (mt * NKS + j) * 1024);
#pragma unroll
      for (int mt = 0; mt < 4; ++mt)
#pragma unroll
        for (int nt = 0; nt < 4; ++nt)
          acc[mt][nt] = __builtin_amdgcn_mfma_f32_16x16x32_bf16(b[nt], a[mt], acc[mt][nt], 0, 0, 0);
    }
  }

  __syncthreads();  // all waves done reading act for this layer

  // epilogue: bias+relu, pack 4 consecutive n per thread -> one ds_write_b64
#pragma unroll
  for (int nt = 0; nt < 4; ++nt) {
    const f32x4 bv = *(const f32x4*)(bias + col0 + nt * 16 + l4 * 4);
    const int slot = l15 + ((nt & 1) * 2 + (l4 >> 1)) * 16;
    const int ksp  = w * 2 + (nt >> 1);
    const int boff = slot * 16 + (l4 & 1) * 8;
#pragma unroll
    for (int mt = 0; mt < 4; ++mt) {
      bf16x4 pk;
#pragma unroll
      for (int r = 0; r < 4; ++r) {
        const float v = acc[mt][nt][r] + bv[r];
        pk[r] = (bf16)(v > 0.f ? v : 0.f);
      }
      *(bf16x4*)(act + (mt * 16 + ksp) * 1024 + boff) = pk;
    }
  }
  __syncthreads();  // act ready for next layer
}

// ---------------------------------------------------------------------------
// Final layer (swapped operands too): lane holds m = mt*16+l15, 4 consecutive
// output cols -> ONE global_store_dwordx4 per frag. No relu.
// ---------------------------------------------------------------------------
template<bool WSPATH>
__device__ __forceinline__ void run_final_layer(
    const bf16* __restrict__ wb, const float* __restrict__ wf,
    const float* __restrict__ bias, const char* __restrict__ act,
    float* __restrict__ gout,
    int w, int l, int l15, int l4)
{
  constexpr int NKS = 16;
  const int mt = w >> 1;
  const int nb = (w & 1) * 2;
  const char* abase = act + mt * 16384 + l * 16;

  f32x4 acc[2];
  acc[0] = f32x4{0.f, 0.f, 0.f, 0.f};
  acc[1] = f32x4{0.f, 0.f, 0.f, 0.f};

  if constexpr (WSPATH) {
    const bf16* bp0 = wb + ((size_t)(nb + 0) * 16 * 64 + l) * 8;
    const bf16* bp1 = wb + ((size_t)(nb + 1) * 16 * 64 + l) * 8;
    bf16x8 B0[2], B1[2];
    B0[0] = *(const bf16x8*)(bp0);
    B0[1] = *(const bf16x8*)(bp1);
#pragma unroll
    for (int j = 0; j < NKS; j += 2) {
      {
        B1[0] = *(const bf16x8*)(bp0 + (size_t)(j + 1) * 512);
        B1[1] = *(const bf16x8*)(bp1 + (size_t)(j + 1) * 512);
        const bf16x8 a = *(const bf16x8*)(abase + j * 1024);
        acc[0] = __builtin_amdgcn_mfma_f32_16x16x32_bf16(B0[0], a, acc[0], 0, 0, 0);
        acc[1] = __builtin_amdgcn_mfma_f32_16x16x32_bf16(B0[1], a, acc[1], 0, 0, 0);
      }
      {
        if (j + 2 < NKS) {
          B0[0] = *(const bf16x8*)(bp0 + (size_t)(j + 2) * 512);
          B0[1] = *(const bf16x8*)(bp1 + (size_t)(j + 2) * 512);
        }
        const bf16x8 a = *(const bf16x8*)(abase + (j + 1) * 1024);
        acc[0] = __builtin_amdgcn_mfma_f32_16x16x32_bf16(B1[0], a, acc[0], 0, 0, 0);
        acc[1] = __builtin_amdgcn_mfma_f32_16x16x32_bf16(B1[1], a, acc[1], 0, 0, 0);
      }
    }
  } else {
    const float* bpf0 = wf + (size_t)((nb + 0) * 16 + l15) * UN + l4 * 8;
    const float* bpf1 = wf + (size_t)((nb + 1) * 16 + l15) * UN + l4 * 8;
#pragma unroll
    for (int j = 0; j < NKS; ++j) {
      const bf16x8 b0 = cvt8(bpf0 + j * 32);
      const bf16x8 b1 = cvt8(bpf1 + j * 32);
      const bf16x8 a = *(const bf16x8*)(abase + j * 1024);
      acc[0] = __builtin_amdgcn_mfma_f32_16x16x32_bf16(b0, a, acc[0], 0, 0, 0);
      acc[1] = __builtin_amdgcn_mfma_f32_16x16x32_bf16(b1, a, acc[1], 0, 0, 0);
    }
  }

#pragma unroll
  for (int i = 0; i < 2; ++i) {
    const f32x4 bv = *(const f32x4*)(bias + (nb + i) * 16 + l4 * 4);
    f32x4 o;
#pragma unroll
    for (int r = 0; r < 4; ++r) o[r] = acc[i][r] + bv[r];
    *(f32x4*)(gout + (size_t)(mt * 16 + l15) * FOUT + (nb + i) * 16 + l4 * 4) = o;
  }
}

template<bool WSPATH>
__global__ __launch_bounds__(512, 2) void mlp_fused(
    const float* __restrict__ x,
    const float* __restrict__ w0f, const float* __restrict__ w1f,
    const float* __restrict__ w2f, const float* __restrict__ w3f,
    const float* __restrict__ b0, const float* __restrict__ b1,
    const float* __restrict__ b2, const float* __restrict__ b3,
    const bf16* __restrict__ wbase,
    float* __restrict__ out)
{
  extern __shared__ char smem[];
  char* act = smem;  // 64 KiB activations, frag order (only LDS use)

  const int tid = threadIdx.x;
  const int w = tid >> 6, l = tid & 63;
  const int l15 = l & 15, l4 = l >> 4;

  // XCD-chunked swizzle (4096 % 8 == 0 -> bijective): each XCD owns one channel
  const int wg = (blockIdx.x & 7) * 512 + (blockIdx.x >> 3);
  const int ch = wg >> 9;
  const int row0 = (wg & 511) * BM;

  const bf16* w0b = wbase + (size_t)ch * UN * FIN;
  const bf16* w1b = wbase + CH * UN * FIN + (size_t)ch * UN * UN;
  const bf16* w2b = wbase + CH * UN * FIN + CH * UN * UN + (size_t)ch * UN * UN;
  const bf16* w3b = wbase + CH * UN * FIN + 2 * CH * UN * UN + (size_t)ch * FOUT * UN;
  const float* w0c = w0f + (size_t)ch * UN * FIN;
  const float* w1c = w1f + (size_t)ch * UN * UN;
  const float* w2c = w2f + (size_t)ch * UN * UN;
  const float* w3c = w3f + (size_t)ch * FOUT * UN;
  const float* b0c = b0 + ch * UN;
  const float* b1c = b1 + ch * UN;
  const float* b2c = b2 + ch * UN;
  const float* b3c = b3 + ch * FOUT;

  // stage x tile (64 x 64 fp32 -> bf16) into act, frag order with NKS=2
  {
    const float* xs = x + (size_t)(ch * SEC + row0) * FIN;
    store_cvt8(act + w * 1024 + l * 16,
               xs + ((w >> 1) * 16 + l15) * FIN + (w & 1) * 32 + l4 * 8);
  }
  __syncthreads();

  run_main_layer<64,  WSPATH>(w0b, w0c, b0c, act, w, l, l15, l4);
  run_main_layer<512, WSPATH>(w1b, w1c, b1c, act, w, l, l15, l4);
  run_main_layer<512, WSPATH>(w2b, w2c, b2c, act, w, l, l15, l4);
  run_final_layer<WSPATH>(w3b, w3c, b3c, act,
                          out + (size_t)(ch * SEC + row0) * FOUT,
                          w, l, l15, l4);
}

// ---------------------------------------------------------------------------
// fp32 -> bf16 weight conversion into d_ws, SWIZZLED to MFMA-fragment order:
// per channel, element (f, ks, l, j) = W[f*16 + (l&15)][ks*32 + (l>>4)*8 + j]
// stored at ((f*NKS + ks)*64 + l)*8 + j. One thread per (ch,f,ks,l) triple.
// (Same frag structure serves the A-operand W-frags.)
// ---------------------------------------------------------------------------
template<int K, int N>
__device__ __forceinline__ void cvt_one(const float* __restrict__ src,
                                        bf16* __restrict__ dst, int t)
{
  constexpr int NKS = K / 32;
  constexpr int perCh = N * K / 8;   // triples per channel (pow2)
  const int ch = t / perCh;
  const int r = t - ch * perCh;
  const int l = r & 63;
  const int p = r >> 6;
  const int ks = p & (NKS - 1);
  const int f = p / NKS;
  const float* s = src + (size_t)ch * N * K + (size_t)(f * 16 + (l & 15)) * K
                 + ks * 32 + (l >> 4) * 8;
  store_cvt8(dst + (size_t)t * 8, s);
}

__global__ void cvt_weights(const float* __restrict__ w0, const float* __restrict__ w1,
                            const float* __restrict__ w2, const float* __restrict__ w3,
                            bf16* __restrict__ o)
{
  constexpr int T0 = CH * UN * FIN / 8;   // 32768 triples
  constexpr int T1 = CH * UN * UN / 8;    // 262144
  constexpr int total = 2 * T0 + 2 * T1;  // 589824
  for (int t = blockIdx.x * blockDim.x + threadIdx.x; t < total;
       t += gridDim.x * blockDim.x) {
    if (t < T0)                cvt_one<FIN, UN>(w0, o, t);
    else if (t < T0 + T1)      cvt_one<UN, UN>(w1, o + CH * UN * FIN, t - T0);
    else if (t < T0 + 2 * T1)  cvt_one<UN, UN>(w2, o + CH * UN * FIN + CH * UN * UN, t - T0 - T1);
    else                       cvt_one<UN, FOUT>(w3, o + CH * UN * FIN + 2 * CH * UN * UN, t - T0 - 2 * T1);
  }
}

extern "C" void kernel_launch(void* const* d_in, const int* in_sizes, int n_in,
                              void* d_out, int out_size, void* d_ws, size_t ws_size,
                              hipStream_t stream)
{
  const float* x  = (const float*)d_in[0];
  const float* w0 = (const float*)d_in[1];
  const float* w1 = (const float*)d_in[2];
  const float* w2 = (const float*)d_in[3];
  const float* w3 = (const float*)d_in[4];
  const float* b0 = (const float*)d_in[5];
  const float* b1 = (const float*)d_in[6];
  const float* b2 = (const float*)d_in[7];
  const float* b3 = (const float*)d_in[8];
  float* out = (float*)d_out;

  const int grid = CH * (SEC / BM);            // 4096 blocks
  const size_t wbytes = (size_t)(2 * CH * UN * FIN + 2 * CH * UN * UN) * 2;  // 9437184

  if (ws_size >= wbytes) {
    bf16* wb = (bf16*)d_ws;
    hipLaunchKernelGGL(cvt_weights, dim3(2304), dim3(256), 0, stream, w0, w1, w2, w3, wb);
    hipFuncSetAttribute(reinterpret_cast<const void*>(mlp_fused<true>),
                        hipFuncAttributeMaxDynamicSharedMemorySize, 65536);
    hipLaunchKernelGGL(mlp_fused<true>, dim3(grid), dim3(512), 65536, stream,
                       x, w0, w1, w2, w3, b0, b1, b2, b3, wb, out);
  } else {
    hipFuncSetAttribute(reinterpret_cast<const void*>(mlp_fused<false>),
                        hipFuncAttributeMaxDynamicSharedMemorySize, 65536);
    hipLaunchKernelGGL(mlp_fused<false>, dim3(grid), dim3(512), 65536, stream,
                       x, w0, w1, w2, w3, b0, b1, b2, b3, (const bf16*)nullptr, out);
  }
}

// Round 9
// 288.810 us; speedup vs baseline: 2.3850x; 1.0486x over previous
//
#include <hip/hip_runtime.h>
#include <hip/hip_bf16.h>

#define CH 8
#define SEC 32768
#define FIN 64
#define FOUT 64
#define UN 512
#define BM 128

typedef __bf16 bf16;
typedef bf16 bf16x8 __attribute__((ext_vector_type(8)));
typedef bf16 bf16x4 __attribute__((ext_vector_type(4)));
typedef float f32x4 __attribute__((ext_vector_type(4)));

// load 8 consecutive fp32 and convert to bf16x8
__device__ __forceinline__ bf16x8 cvt8(const float* __restrict__ src) {
  f32x4 u0 = *(const f32x4*)src;
  f32x4 u1 = *(const f32x4*)(src + 4);
  bf16x8 v;
  v[0] = (bf16)u0[0]; v[1] = (bf16)u0[1]; v[2] = (bf16)u0[2]; v[3] = (bf16)u0[3];
  v[4] = (bf16)u1[0]; v[5] = (bf16)u1[1]; v[6] = (bf16)u1[2]; v[7] = (bf16)u1[3];
  return v;
}

__device__ __forceinline__ void store_cvt8(void* dst, const float* __restrict__ src) {
  *(bf16x8*)dst = cvt8(src);
}

// ---------------------------------------------------------------------------
// Main layer, BM=128, 16 waves, SWAPPED MFMA operands (acc = mfma(W, X)).
// act layout: [8 gmt][NKS][64 lanes][16B] (128 KiB at K=512).
// Wave tile 64x64: wm = w>>3 -> rows wm*64.., local mt 0..3 (gmt = wm*4+mt);
//                  wn = w&7  -> cols wn*64.., nt 0..3.
// B: single-buffered global->reg from swizzled d_ws (wm pair shares lines via
// L1). Regs/wave ~110 < 128 -> 16 waves/CU (4/SIMD), no spill.
// D[n][m] lane map: m = l15 (batch row), n = l4*4+r (4 consecutive features)
// -> epilogue packs one ds_write_b64 per (mt,nt) in next layer's frag order:
//    ksp = wn*2 + (nt>>1); slot-lane = l15 + 16*((nt&1)*2 + (l4>>1));
//    byte = (l4&1)*8.
// ---------------------------------------------------------------------------
template<int K, bool WSPATH>
__device__ __forceinline__ void run_main_layer(
    const bf16* __restrict__ wb,   // swizzled layout when WSPATH
    const float* __restrict__ wf,  // raw [N][K] fp32 fallback
    const float* __restrict__ bias, char* __restrict__ act,
    int w, int l, int l15, int l4, int wm, int wn)
{
  constexpr int NKS = K / 32;
  const int col0 = wn * 64;
  const char* abase = act + wm * (4 * NKS * 1024) + l * 16;

  f32x4 acc[4][4];   // [mt][nt]
#pragma unroll
  for (int mt = 0; mt < 4; ++mt)
#pragma unroll
    for (int nt = 0; nt < 4; ++nt)
      acc[mt][nt] = f32x4{0.f, 0.f, 0.f, 0.f};

  if constexpr (WSPATH) {
    const bf16* bp = wb + ((size_t)(wn * 4) * NKS * 64 + l) * 8;
#pragma unroll
    for (int j = 0; j < NKS; ++j) {
      bf16x8 B[4], a[4];
#pragma unroll
      for (int i = 0; i < 4; ++i)
        B[i] = *(const bf16x8*)(bp + (size_t)(i * NKS + j) * 512);
#pragma unroll
      for (int mt = 0; mt < 4; ++mt)
        a[mt] = *(const bf16x8*)(abase + (mt * NKS + j) * 1024);
      __builtin_amdgcn_s_setprio(1);
#pragma unroll
      for (int mt = 0; mt < 4; ++mt)
#pragma unroll
        for (int nt = 0; nt < 4; ++nt)
          acc[mt][nt] = __builtin_amdgcn_mfma_f32_16x16x32_bf16(B[nt], a[mt], acc[mt][nt], 0, 0, 0);
      __builtin_amdgcn_s_setprio(0);
    }
  } else {
    const float* bpf[4];
#pragma unroll
    for (int nt = 0; nt < 4; ++nt)
      bpf[nt] = wf + (size_t)(col0 + nt * 16 + l15) * K + l4 * 8;
#pragma unroll
    for (int j = 0; j < NKS; ++j) {
      bf16x8 a[4], b[4];
#pragma unroll
      for (int nt = 0; nt < 4; ++nt) b[nt] = cvt8(bpf[nt] + j * 32);
#pragma unroll
      for (int mt = 0; mt < 4; ++mt)
        a[mt] = *(const bf16x8*)(abase + (mt * NKS + j) * 1024);
#pragma unroll
      for (int mt = 0; mt < 4; ++mt)
#pragma unroll
        for (int nt = 0; nt < 4; ++nt)
          acc[mt][nt] = __builtin_amdgcn_mfma_f32_16x16x32_bf16(b[nt], a[mt], acc[mt][nt], 0, 0, 0);
    }
  }

  __syncthreads();  // all waves done reading act for this layer

  // epilogue: bias+relu, pack 4 consecutive n per thread -> one ds_write_b64
#pragma unroll
  for (int nt = 0; nt < 4; ++nt) {
    const f32x4 bv = *(const f32x4*)(bias + col0 + nt * 16 + l4 * 4);
    const int slot = l15 + ((nt & 1) * 2 + (l4 >> 1)) * 16;
    const int ksp  = wn * 2 + (nt >> 1);
    const int boff = slot * 16 + (l4 & 1) * 8;
#pragma unroll
    for (int mt = 0; mt < 4; ++mt) {
      bf16x4 pk;
#pragma unroll
      for (int r = 0; r < 4; ++r) {
        const float v = acc[mt][nt][r] + bv[r];
        pk[r] = (bf16)(v > 0.f ? v : 0.f);
      }
      *(bf16x4*)(act + ((wm * 4 + mt) * 16 + ksp) * 1024 + boff) = pk;
    }
  }
  __syncthreads();  // act ready for next layer
}

// ---------------------------------------------------------------------------
// Final layer, BM=128, 16 waves, swapped operands. rg = w>>2 -> rows rg*32
// (2 mtiles), cg = w&3 -> 16-col frag. Lane holds m = mt*16+l15 and 4
// consecutive cols -> ONE global_store_dwordx4 per mtile. No relu.
// ---------------------------------------------------------------------------
template<bool WSPATH>
__device__ __forceinline__ void run_final_layer(
    const bf16* __restrict__ wb, const float* __restrict__ wf,
    const float* __restrict__ bias, const char* __restrict__ act,
    float* __restrict__ gout,
    int w, int l, int l15, int l4)
{
  constexpr int NKS = 16;
  const int rg = w >> 2, cg = w & 3;
  const char* abase = act + (rg * 2) * (NKS * 1024) + l * 16;

  f32x4 acc[2];
  acc[0] = f32x4{0.f, 0.f, 0.f, 0.f};
  acc[1] = f32x4{0.f, 0.f, 0.f, 0.f};

  if constexpr (WSPATH) {
    const bf16* bp = wb + ((size_t)cg * 16 * 64 + l) * 8;
#pragma unroll
    for (int j = 0; j < NKS; ++j) {
      const bf16x8 b  = *(const bf16x8*)(bp + (size_t)j * 512);
      const bf16x8 a0 = *(const bf16x8*)(abase + j * 1024);
      const bf16x8 a1 = *(const bf16x8*)(abase + (NKS + j) * 1024);
      acc[0] = __builtin_amdgcn_mfma_f32_16x16x32_bf16(b, a0, acc[0], 0, 0, 0);
      acc[1] = __builtin_amdgcn_mfma_f32_16x16x32_bf16(b, a1, acc[1], 0, 0, 0);
    }
  } else {
    const float* bpf = wf + (size_t)(cg * 16 + l15) * UN + l4 * 8;
#pragma unroll
    for (int j = 0; j < NKS; ++j) {
      const bf16x8 b  = cvt8(bpf + j * 32);
      const bf16x8 a0 = *(const bf16x8*)(abase + j * 1024);
      const bf16x8 a1 = *(const bf16x8*)(abase + (NKS + j) * 1024);
      acc[0] = __builtin_amdgcn_mfma_f32_16x16x32_bf16(b, a0, acc[0], 0, 0, 0);
      acc[1] = __builtin_amdgcn_mfma_f32_16x16x32_bf16(b, a1, acc[1], 0, 0, 0);
    }
  }

  const f32x4 bv = *(const f32x4*)(bias + cg * 16 + l4 * 4);
#pragma unroll
  for (int i = 0; i < 2; ++i) {
    f32x4 o;
#pragma unroll
    for (int r = 0; r < 4; ++r) o[r] = acc[i][r] + bv[r];
    *(f32x4*)(gout + (size_t)((rg * 2 + i) * 16 + l15) * FOUT + cg * 16 + l4 * 4) = o;
  }
}

template<bool WSPATH>
__global__ __launch_bounds__(1024, 4) void mlp_fused(
    const float* __restrict__ x,
    const float* __restrict__ w0f, const float* __restrict__ w1f,
    const float* __restrict__ w2f, const float* __restrict__ w3f,
    const float* __restrict__ b0, const float* __restrict__ b1,
    const float* __restrict__ b2, const float* __restrict__ b3,
    const bf16* __restrict__ wbase,
    float* __restrict__ out)
{
  extern __shared__ char smem[];
  char* act = smem;  // 128 KiB activations, frag order (only LDS use)

  const int tid = threadIdx.x;
  const int w = tid >> 6, l = tid & 63;
  const int l15 = l & 15, l4 = l >> 4;
  const int wm = w >> 3, wn = w & 7;

  // XCD-chunked swizzle (2048 % 8 == 0 -> bijective): each XCD owns one channel
  const int wg = (blockIdx.x & 7) * 256 + (blockIdx.x >> 3);
  const int ch = wg >> 8;
  const int row0 = (wg & 255) * BM;

  const bf16* w0b = wbase + (size_t)ch * UN * FIN;
  const bf16* w1b = wbase + CH * UN * FIN + (size_t)ch * UN * UN;
  const bf16* w2b = wbase + CH * UN * FIN + CH * UN * UN + (size_t)ch * UN * UN;
  const bf16* w3b = wbase + CH * UN * FIN + 2 * CH * UN * UN + (size_t)ch * FOUT * UN;
  const float* w0c = w0f + (size_t)ch * UN * FIN;
  const float* w1c = w1f + (size_t)ch * UN * UN;
  const float* w2c = w2f + (size_t)ch * UN * UN;
  const float* w3c = w3f + (size_t)ch * FOUT * UN;
  const float* b0c = b0 + ch * UN;
  const float* b1c = b1 + ch * UN;
  const float* b2c = b2 + ch * UN;
  const float* b3c = b3 + ch * FOUT;

  // stage x tile (128 x 64 fp32 -> bf16) into act: slot w = gmt*2 + ks
  {
    const float* xs = x + (size_t)(ch * SEC + row0) * FIN;
    store_cvt8(act + w * 1024 + l * 16,
               xs + ((w >> 1) * 16 + l15) * FIN + (w & 1) * 32 + l4 * 8);
  }
  __syncthreads();

  run_main_layer<64,  WSPATH>(w0b, w0c, b0c, act, w, l, l15, l4, wm, wn);
  run_main_layer<512, WSPATH>(w1b, w1c, b1c, act, w, l, l15, l4, wm, wn);
  run_main_layer<512, WSPATH>(w2b, w2c, b2c, act, w, l, l15, l4, wm, wn);
  run_final_layer<WSPATH>(w3b, w3c, b3c, act,
                          out + (size_t)(ch * SEC + row0) * FOUT,
                          w, l, l15, l4);
}

// ---------------------------------------------------------------------------
// fp32 -> bf16 weight conversion into d_ws, SWIZZLED to MFMA-fragment order:
// per channel, element (f, ks, l, j) = W[f*16 + (l&15)][ks*32 + (l>>4)*8 + j]
// stored at ((f*NKS + ks)*64 + l)*8 + j.
// ---------------------------------------------------------------------------
template<int K, int N>
__device__ __forceinline__ void cvt_one(const float* __restrict__ src,
                                        bf16* __restrict__ dst, int t)
{
  constexpr int NKS = K / 32;
  constexpr int perCh = N * K / 8;   // triples per channel (pow2)
  const int ch = t / perCh;
  const int r = t - ch * perCh;
  const int l = r & 63;
  const int p = r >> 6;
  const int ks = p & (NKS - 1);
  const int f = p / NKS;
  const float* s = src + (size_t)ch * N * K + (size_t)(f * 16 + (l & 15)) * K
                 + ks * 32 + (l >> 4) * 8;
  store_cvt8(dst + (size_t)t * 8, s);
}

__global__ void cvt_weights(const float* __restrict__ w0, const float* __restrict__ w1,
                            const float* __restrict__ w2, const float* __restrict__ w3,
                            bf16* __restrict__ o)
{
  constexpr int T0 = CH * UN * FIN / 8;   // 32768 triples
  constexpr int T1 = CH * UN * UN / 8;    // 262144
  constexpr int total = 2 * T0 + 2 * T1;  // 589824
  for (int t = blockIdx.x * blockDim.x + threadIdx.x; t < total;
       t += gridDim.x * blockDim.x) {
    if (t < T0)                cvt_one<FIN, UN>(w0, o, t);
    else if (t < T0 + T1)      cvt_one<UN, UN>(w1, o + CH * UN * FIN, t - T0);
    else if (t < T0 + 2 * T1)  cvt_one<UN, UN>(w2, o + CH * UN * FIN + CH * UN * UN, t - T0 - T1);
    else                       cvt_one<UN, FOUT>(w3, o + CH * UN * FIN + 2 * CH * UN * UN, t - T0 - 2 * T1);
  }
}

extern "C" void kernel_launch(void* const* d_in, const int* in_sizes, int n_in,
                              void* d_out, int out_size, void* d_ws, size_t ws_size,
                              hipStream_t stream)
{
  const float* x  = (const float*)d_in[0];
  const float* w0 = (const float*)d_in[1];
  const float* w1 = (const float*)d_in[2];
  const float* w2 = (const float*)d_in[3];
  const float* w3 = (const float*)d_in[4];
  const float* b0 = (const float*)d_in[5];
  const float* b1 = (const float*)d_in[6];
  const float* b2 = (const float*)d_in[7];
  const float* b3 = (const float*)d_in[8];
  float* out = (float*)d_out;

  const int grid = CH * (SEC / BM);            // 2048 blocks
  const size_t wbytes = (size_t)(2 * CH * UN * FIN + 2 * CH * UN * UN) * 2;  // 9437184

  if (ws_size >= wbytes) {
    bf16* wb = (bf16*)d_ws;
    hipLaunchKernelGGL(cvt_weights, dim3(2304), dim3(256), 0, stream, w0, w1, w2, w3, wb);
    hipFuncSetAttribute(reinterpret_cast<const void*>(mlp_fused<true>),
                        hipFuncAttributeMaxDynamicSharedMemorySize, 131072);
    hipLaunchKernelGGL(mlp_fused<true>, dim3(grid), dim3(1024), 131072, stream,
                       x, w0, w1, w2, w3, b0, b1, b2, b3, wb, out);
  } else {
    hipFuncSetAttribute(reinterpret_cast<const void*>(mlp_fused<false>),
                        hipFuncAttributeMaxDynamicSharedMemorySize, 131072);
    hipLaunchKernelGGL(mlp_fused<false>, dim3(grid), dim3(1024), 131072, stream,
                       x, w0, w1, w2, w3, b0, b1, b2, b3, (const bf16*)nullptr, out);
  }
}